// Round 10
// baseline (1910.502 us; speedup 1.0000x reference)
//
#include <hip/hip_runtime.h>
#include <hip/hip_bf16.h>
#include <cstdint>

#define DEV static __device__ __forceinline__

typedef short bf16x8 __attribute__((ext_vector_type(8)));
typedef float f32x4 __attribute__((ext_vector_type(4)));
typedef unsigned short bfu8 __attribute__((ext_vector_type(8)));

// ---------------- workspace layout (bytes) ----------------
constexpr size_t CORR0_OFF = 0;                        // (2,2048,2048) bf16
constexpr size_t F1_OFF    = CORR0_OFF + 33554432ull + 11010048ull;  // (2,2048,256) bf16
constexpr size_t F2_OFF    = F1_OFF    + 2097152ull;
constexpr size_t INP_OFF   = F2_OFF    + 2097152ull;   // (4096,128) bf16
constexpr size_t HF_OFF    = INP_OFF   + 1048576ull;   // (4096,512) f32
constexpr size_t HB_OFF    = HF_OFF    + 8388608ull;   // (4096,512) bf16
constexpr size_t RH_OFF    = HB_OFF    + 4194304ull;   // (4096,512) bf16
constexpr size_t Z_OFF     = RH_OFF    + 4194304ull;   // (4096,512) bf16 z-gate
constexpr size_t CP1_OFF   = Z_OFF     + 8388608ull;   // (4096,1536) bf16
constexpr size_t CP2_OFF   = CP1_OFF   + 25165824ull;
constexpr size_t WA1_OFF   = CP2_OFF   + 25165824ull;  // frag-packed weights
constexpr size_t WA2_OFF   = WA1_OFF   + 5242880ull;
constexpr size_t WB1_OFF   = WA2_OFF   + 5242880ull;
constexpr size_t WB2_OFF   = WB1_OFF   + 2621440ull;
constexpr size_t WI1_OFF   = WB2_OFF   + 2621440ull;
constexpr size_t WI2_OFF   = WI1_OFF   + 1966080ull;
constexpr size_t WFIN_OFF  = WI2_OFF   + 1966080ull;
constexpr size_t OP_OFF    = WFIN_OFF  + 2359296ull;   // (4096,256) f32
constexpr size_t ZP_OFF    = OP_OFF    + 4194304ull;   // 1024 B zero page

DEV unsigned short f2bf(float f) {
  unsigned int u = __float_as_uint(f);
  u += 0x7fffu + ((u >> 16) & 1u);
  return (unsigned short)(u >> 16);
}
DEV float bf2f(unsigned short u) { return __uint_as_float(((unsigned)u) << 16); }

DEV void gload16(const void* src, void* dst) {
  __builtin_amdgcn_global_load_lds(
      (const __attribute__((address_space(1))) void*)src,
      (__attribute__((address_space(3))) void*)dst, 16, 0, 0);
}

// ---------------- prep: f1/f2 bf16, tanh->h[324..451], relu->inp, pads, zero page
__launch_bounds__(256)
__global__ void prep_kernel(const float* __restrict__ x, unsigned short* f1, unsigned short* f2,
                            float* h_f32, unsigned short* h_b16, unsigned short* inp, float* zp) {
  int bx = blockIdx.x;                 // 0..8191
  int s = bx >> 11, n = bx & 2047, c = (int)threadIdx.x;
  float v = x[((size_t)(s * 2048 + n)) * 256 + c];
  int b = s >> 1;
  unsigned short bv = f2bf(v);
  size_t p = (size_t)b * 2048 + n;
  if (s & 1) {
    f2[p * 256 + c] = bv;
  } else {
    f1[p * 256 + c] = bv;
    if (c < 128) {
      float tv = tanhf(v);
      h_f32[p * 512 + 324 + c] = tv;
      h_b16[p * 512 + 324 + c] = f2bf(tv);
    } else {
      float rv = fmaxf(v, 0.f);
      inp[p * 128 + (c - 128)] = f2bf(rv);
    }
    if (c < 60) { h_f32[p * 512 + 452 + c] = 0.f; h_b16[p * 512 + 452 + c] = 0; }
  }
  if (bx == 0) zp[c] = 0.f;
}

// ---------------- weight repack into MFMA-fragment order
// dst layout: [ng][t][ck][q][l15][e] : (((ng*TAPS+t)*CPT+ck)*8+q)*128 + l15*8 + e
// so a wave reading (ng,t,ck,ks) gets 1KB contiguous at lane*16.
DEV void wprep_body(const float* s0, const float* s1, const float* s2,
                    unsigned short* dst, long rel, int CPT, int TAPS, int Kvalid, int icOff,
                    int sOC, int sIC) {
  long idx = rel * 256 + threadIdx.x;
  int low = (int)(idx & 127); int l15 = low >> 3, e = low & 7;
  long rest = idx >> 7;
  int q = (int)(rest & 7); rest >>= 3;
  int ck = (int)(rest % CPT); rest /= CPT;
  int t  = (int)(rest % TAPS); rest /= TAPS;
  int ng = (int)rest;
  int n = ng * 16 + l15;
  int k = ck * 64 + q * 8 + e;
  int sec = n >> 9, ocl = n & 511;
  const float* sp = (sec == 0) ? s0 : (sec == 1 ? s1 : s2);
  float v = 0.f;
  if (ocl < 452 && k < Kvalid) v = sp[(size_t)ocl * sOC + (size_t)(icOff + k) * sIC + t];
  dst[idx] = f2bf(v);
}

struct WPAll {
  const float *wz1, *wr1, *wq1, *wz2, *wr2, *wq2, *wc;
  unsigned short *wA1, *wB1, *wi1, *wA2, *wB2, *wi2, *wfn;
};

__launch_bounds__(256)
__global__ void wprep_all(WPAll a) {
  long b = blockIdx.x;
  if      (b < 10240) wprep_body(a.wz1, a.wr1, nullptr, a.wA1, b,         8, 5, 452, 0,   2900, 5);
  else if (b < 15360) wprep_body(a.wq1, nullptr, nullptr, a.wB1, b-10240, 8, 5, 452, 0,   2900, 5);
  else if (b < 19200) wprep_body(a.wz1, a.wr1, a.wq1,   a.wi1, b-15360,   2, 5, 128, 452, 2900, 5);
  else if (b < 29440) wprep_body(a.wz2, a.wr2, nullptr, a.wA2, b-19200,   8, 5, 452, 0,   2900, 5);
  else if (b < 34560) wprep_body(a.wq2, nullptr, nullptr, a.wB2, b-29440, 8, 5, 452, 0,   2900, 5);
  else if (b < 38400) wprep_body(a.wz2, a.wr2, a.wq2,   a.wi2, b-34560,   2, 5, 128, 452, 2900, 5);
  else                wprep_body(a.wc,  nullptr, nullptr, a.wfn, b-38400, 8, 9, 452, 0,   4068, 9);
}

// ---------------- fused pyramid + corr lookup (pyramid stays in LDS)
__launch_bounds__(256)
__global__ void pyrlook_kernel(const unsigned short* __restrict__ corr0,
                               float* h_f32, unsigned short* h_b16) {
  __shared__ float s0[2048];
  __shared__ float s1[512];
  __shared__ float s2[128];
  __shared__ float s3[32];
  int bn = blockIdx.x, tid = (int)threadIdx.x;
  bfu8 v8 = ((const bfu8*)(corr0 + (size_t)bn * 2048))[tid];
  #pragma unroll
  for (int j = 0; j < 8; ++j) s0[tid * 8 + j] = bf2f(v8[j]);
  __syncthreads();
  for (int o = tid; o < 512; o += 256) {
    int yy = o >> 5, xx = o & 31;
    s1[o] = 0.25f * (s0[(yy*2)*64 + xx*2] + s0[(yy*2)*64 + xx*2 + 1] +
                     s0[(yy*2+1)*64 + xx*2] + s0[(yy*2+1)*64 + xx*2 + 1]);
  }
  __syncthreads();
  if (tid < 128) {
    int yy = tid >> 4, xx = tid & 15;
    s2[tid] = 0.25f * (s1[(yy*2)*32 + xx*2] + s1[(yy*2)*32 + xx*2 + 1] +
                       s1[(yy*2+1)*32 + xx*2] + s1[(yy*2+1)*32 + xx*2 + 1]);
  }
  __syncthreads();
  if (tid < 32) {
    int yy = tid >> 3, xx = tid & 7;
    s3[tid] = 0.25f * (s2[(yy*2)*16 + xx*2] + s2[(yy*2)*16 + xx*2 + 1] +
                       s2[(yy*2+1)*16 + xx*2] + s2[(yy*2+1)*16 + xx*2 + 1]);
  }
  __syncthreads();
  int x = bn & 63, y = (bn >> 6) & 31;
  for (int ch = tid; ch < 324; ch += 256) {
    int lvl = ch / 81, w = ch % 81;
    int di = w / 9 - 4, dj = w % 9 - 4;
    const float* sl = (lvl == 0) ? s0 : (lvl == 1) ? s1 : (lvl == 2) ? s2 : s3;
    int wl = 64 >> lvl, hl = 32 >> lvl;
    float sx = (float)x / (float)(1 << lvl) + (float)di;
    float sy = (float)y / (float)(1 << lvl) + (float)dj;
    float fx0 = floorf(sx), fy0 = floorf(sy);
    int x0 = (int)fx0, y0 = (int)fy0;
    float wx1 = sx - fx0, wx0 = 1.f - wx1;
    float wy1 = sy - fy0, wy0 = 1.f - wy1;
    float acc = 0.f;
    if (x0 >= 0 && x0 < wl && y0 >= 0 && y0 < hl)         acc += sl[y0*wl + x0] * wx0 * wy0;
    if (x0+1 >= 0 && x0+1 < wl && y0 >= 0 && y0 < hl)     acc += sl[y0*wl + x0+1] * wx1 * wy0;
    if (x0 >= 0 && x0 < wl && y0+1 >= 0 && y0+1 < hl)     acc += sl[(y0+1)*wl + x0] * wx0 * wy1;
    if (x0+1 >= 0 && x0+1 < wl && y0+1 >= 0 && y0+1 < hl) acc += sl[(y0+1)*wl + x0+1] * wx1 * wy1;
    h_f32[(size_t)bn * 512 + ch] = acc;
    h_b16[(size_t)bn * 512 + ch] = f2bf(acc);
  }
}

// ---------------- GEMM-conv engines ----------------
constexpr int KN = 0, KH = 1, KV = 2, KF = 3;     // shift kinds
constexpr int EC = 0, EP = 1, EA = 2, EB = 3, EF = 4;  // epilogues

struct GArgs {
  const char* A; int AstrB; long AbatchB;
  const char* B; int KelB;  long BbatchB;
  const float* e0; const float* e1; const float* e2;
  const unsigned short* b0;          // bf16 Cp source for EA/EB
  const unsigned short* b1;          // bf16 aux read (h_b16 for EA, z for EB)
  float* f0; unsigned short* u0; unsigned short* u1;
  long CbatchE;
  const char* zp;
};

template<int MT>
DEV void stage_act(const char* Ab, int AstrB, char* ldsbuf, int ckOff, int p0) {
  #pragma unroll
  for (int it = 0; it < (MT * 8) / 256; ++it) {
    int gi = it * 256 + (int)threadIdx.x;
    int row = gi >> 3, gs = gi & 7;
    int gl = gs ^ (row & 7);
    int p = p0 + row;
    const char* src = Ab + (size_t)p * (size_t)AstrB + ckOff + gl * 16;
    char* dst = ldsbuf + ((size_t)(it * 256 + ((int)threadIdx.x & ~63)) * 16);
    gload16(src, dst);
  }
}

template<int NT>
DEV void stage_wk(const char* Bb, int KelB, char* ldsbuf, int ckOff, int n0) {
  #pragma unroll
  for (int it = 0; it < (NT * 8) / 256; ++it) {
    int gi = it * 256 + (int)threadIdx.x;
    int row = gi >> 3, gs = gi & 7;
    int gl = gs ^ (row & 7);
    int n = n0 + row;
    const char* src = Bb + (size_t)n * (size_t)KelB + ckOff + gl * 16;
    char* dst = ldsbuf + ((size_t)(it * 256 + ((int)threadIdx.x & ~63)) * 16);
    gload16(src, dst);
  }
}

template<int Mf, int Nf, int WM, int WN>
DEV void compute_chunk(const char* lA, const char* lB, f32x4 acc[Mf][Nf], int wm, int wn) {
  const int lane = (int)threadIdx.x & 63;
  const int l15 = lane & 15, g = lane >> 4;
  #pragma unroll
  for (int ks = 0; ks < 2; ++ks) {
    bf16x8 a[Mf], b[Nf];
    int q = ks * 4 + g;
    #pragma unroll
    for (int mf = 0; mf < Mf; ++mf) {
      int r = wm * WM + mf * 16 + l15;
      a[mf] = *(const bf16x8*)(lA + r * 128 + ((q ^ (r & 7)) * 16));
    }
    #pragma unroll
    for (int nf = 0; nf < Nf; ++nf) {
      int r = wn * WN + nf * 16 + l15;
      b[nf] = *(const bf16x8*)(lB + r * 128 + ((q ^ (r & 7)) * 16));
    }
    #pragma unroll
    for (int mf = 0; mf < Mf; ++mf)
      #pragma unroll
      for (int nf = 0; nf < Nf; ++nf)
        acc[mf][nf] = __builtin_amdgcn_mfma_f32_16x16x32_bf16(a[mf], b[nf], acc[mf][nf], 0, 0, 0);
  }
}

// shared epilogue
template<int EPI>
DEV void epilogue_store(const GArgs& g, float v, int p, int ng, int bz) {
  if constexpr (EPI == EC) {
    g.u0[(size_t)bz * (size_t)g.CbatchE + (size_t)p * 2048 + ng] = f2bf(v * 0.0625f);
  } else if constexpr (EPI == EP) {
    float bias;
    if (ng < 512)       bias = (ng < 452) ? g.e0[ng] : 0.f;
    else if (ng < 1024) bias = (ng - 512 < 452) ? g.e1[ng - 512] : 0.f;
    else                bias = (ng - 1024 < 452) ? g.e2[ng - 1024] : 0.f;
    g.u0[(size_t)p * 1536 + ng] = f2bf(v + bias);
  } else if constexpr (EPI == EA) {
    float pre = v + bf2f(g.b0[(size_t)p * 1536 + ng]);
    float s = 1.f / (1.f + __expf(-pre));
    if (ng < 512) {
      g.u1[(size_t)p * 512 + ng] = f2bf(s);                       // z gate (bf16)
    } else {
      int oc = ng - 512;
      float rh = s * bf2f(g.b1[(size_t)p * 512 + oc]);            // sigmoid(r) * h_b16
      g.u0[(size_t)p * 512 + oc] = f2bf(rh);
    }
  } else if constexpr (EPI == EB) {
    float pre = v + bf2f(g.b0[(size_t)p * 1536 + 1024 + ng]);
    float e = __expf(-2.f * fabsf(pre));
    float tt = (1.f - e) / (1.f + e);
    float qv = (pre < 0.f) ? -tt : tt;
    float z = bf2f(g.b1[(size_t)p * 512 + ng]);                   // z gate (bf16)
    float ho = g.e2[(size_t)p * 512 + ng];                        // f32 master h
    float hn = (1.f - z) * ho + z * qv;
    g.f0[(size_t)p * 512 + ng] = hn;
    g.u0[(size_t)p * 512 + ng] = f2bf(hn);
  } else {  // EF
    float r = fmaxf(v + g.e0[ng], 0.f);
    g.f0[(size_t)p * 256 + ng] = r;
  }
}

// plain per-chunk GEMM (corr only: KN, no tap shifts), bf16 output
template<int MT, int NT, int WSM, int EPI, int CPT, int MINB>
__launch_bounds__(256, MINB)
__global__ void kgemm(GArgs g) {
  constexpr int WSN = 4 / WSM;
  constexpr int WM = MT / WSM, WN = NT / WSN, Mf = WM / 16, Nf = WN / 16;
  constexpr int BUFB = (MT + NT) * 128;
  __shared__ __attribute__((aligned(16))) char lds[2 * BUFB];
  const int p0 = blockIdx.x * MT, n0 = blockIdx.y * NT;
  const int bz = blockIdx.z;
  const char* Ab = g.A + (size_t)bz * (size_t)g.AbatchB;
  const char* Bb = g.B + (size_t)bz * (size_t)g.BbatchB;
  const int wave = (int)threadIdx.x >> 6;
  const int wm = wave / WSN, wn = wave % WSN;
  f32x4 acc[Mf][Nf] = {};

  auto do_stage = [&](int buf, int c) {
    char* base = lds + (size_t)buf * BUFB;
    stage_act<MT>(Ab, g.AstrB, base, c * 128, p0);
    stage_wk<NT>(Bb, g.KelB, base + MT * 128, c * 128, n0);
  };

  do_stage(0, 0);
  asm volatile("s_waitcnt vmcnt(0)" ::: "memory");
  __builtin_amdgcn_s_barrier();
  asm volatile("" ::: "memory");

  #pragma unroll 1
  for (int c = 0; c < CPT; ++c) {
    int cur = c & 1;
    if (c + 1 < CPT) do_stage(cur ^ 1, c + 1);
    const char* base = lds + (size_t)cur * BUFB;
    compute_chunk<Mf, Nf, WM, WN>(base, base + MT * 128, acc, wm, wn);
    asm volatile("s_waitcnt vmcnt(0)" ::: "memory");
    __builtin_amdgcn_s_barrier();
    asm volatile("" ::: "memory");
  }

  const int lane = (int)threadIdx.x & 63;
  const int l15 = lane & 15, gq = lane >> 4;
  #pragma unroll
  for (int mf = 0; mf < Mf; ++mf)
    #pragma unroll
    for (int nf = 0; nf < Nf; ++nf)
      #pragma unroll
      for (int j = 0; j < 4; ++j) {
        int p = p0 + wm * WM + mf * 16 + gq * 4 + j;
        int ng = n0 + wn * WN + nf * 16 + l15;
        epilogue_store<EPI>(g, acc[mf][nf][j], p, ng, bz);
      }
}

// tap-merged conv GEMM, B read DIRECT from global (frag-packed, L2-resident)
// -> LDS holds only A (double-buffered), 1 barrier per chunk.
template<int MT, int NT, int WSM, int KIND, int EPI, int TAPS, int CPT, int MINB>
__launch_bounds__(256, MINB)
__global__ void tgemm(GArgs g) {
  constexpr int Gsz = (KIND == KV) ? 32 : 64;
  constexpr int G   = (KIND == KF) ? 3 : MT / Gsz;
  constexpr int S   = (KIND == KF) ? 66 : Gsz + 4;
  constexpr int RA  = G * S;
  constexpr int RAP = (RA + 7) & ~7;                 // pad to whole waves
  constexpr int ITA = (RAP * 8 + 255) / 256;
  constexpr int WSN = 4 / WSM;
  constexpr int WM = MT / WSM, WN = NT / WSN;
  constexpr int Mf = WM / 16, Nf = WN / 16;
  __shared__ __attribute__((aligned(16))) char ldsA[2][RAP * 128];

  const int tid = (int)threadIdx.x;
  const int pg = blockIdx.x * MT;
  const int bz = pg >> 11;
  const int q0 = pg & 2047;
  const int bbase = bz << 11;
  const int n0 = blockIdx.y * NT;
  const char* Ab = g.A + (size_t)bbase * (size_t)g.AstrB;
  const int wave = tid >> 6;
  const int wm = wave / WSN, wn = wave % WSN;
  const int lane = tid & 63;
  const int l15 = lane & 15, gq = lane >> 4;
  const int ng0 = (n0 + wn * WN) >> 4;              // B frag col-group base
  f32x4 acc[Mf][Nf] = {};

  auto stageA = [&](int buf, int ck) {
    #pragma unroll
    for (int it = 0; it < ITA; ++it) {
      int gi = it * 256 + tid;
      if (ITA * 256 > RAP * 8 && gi >= RAP * 8) continue;   // whole-wave guard
      int sr = gi >> 3, gs = gi & 7;
      int gl = gs ^ (sr & 7);
      bool valid; int gpos;
      if constexpr (KIND == KF) {
        int grp = sr / 66, qq = sr - grp * 66;
        int y = (q0 >> 6) + grp - 1, x = qq - 1;
        valid = (sr < RA) && (qq >= 1) && (qq < 65) && ((unsigned)y < 32u);
        gpos = (y << 6) + x;
      } else {
        int grp = (G == 1) ? 0 : (sr / S);
        int qq = sr - grp * S;
        valid = (sr < RA) && (qq >= 2) && (qq < Gsz + 2);
        int s = q0 + grp * Gsz + (qq - 2);
        if constexpr (KIND == KH) gpos = s;
        else gpos = ((s & 31) << 6) + (s >> 5);
      }
      const char* src = valid ? (Ab + (size_t)gpos * (size_t)g.AstrB + ck * 128 + gl * 16)
                              : (g.zp + gl * 16);
      gload16(src, &ldsA[buf][(size_t)(it * 256 + (tid & ~63)) * 16]);
    }
  };

  auto computeC = [&](const char* lA, int ck) {
    #pragma unroll 2
    for (int t = 0; t < TAPS; ++t) {
      #pragma unroll
      for (int ks = 0; ks < 2; ++ks) {
        int q = ks * 4 + gq;
        bf16x8 a[Mf], b[Nf];
        #pragma unroll
        for (int nf = 0; nf < Nf; ++nf) {
          size_t boff = ((((size_t)(ng0 + nf) * TAPS + t) * CPT + ck) * 2 + ks) * 1024
                        + (size_t)lane * 16;
          b[nf] = *(const bf16x8*)(g.B + boff);
        }
        #pragma unroll
        for (int mf = 0; mf < Mf; ++mf) {
          int m = wm * WM + mf * 16 + l15;
          int r;
          if constexpr (KIND == KF) r = (t / 3) * 66 + (m & 63) + (t % 3);
          else r = (m / Gsz) * S + (m % Gsz) + t;
          a[mf] = *(const bf16x8*)(lA + r * 128 + ((q ^ (r & 7)) * 16));
        }
        #pragma unroll
        for (int mf = 0; mf < Mf; ++mf)
          #pragma unroll
          for (int nf = 0; nf < Nf; ++nf)
            acc[mf][nf] = __builtin_amdgcn_mfma_f32_16x16x32_bf16(a[mf], b[nf], acc[mf][nf], 0, 0, 0);
      }
    }
  };

  stageA(0, 0);
  asm volatile("s_waitcnt vmcnt(0)" ::: "memory");
  __builtin_amdgcn_s_barrier();
  asm volatile("" ::: "memory");

  #pragma unroll 1
  for (int ck = 0; ck < CPT; ++ck) {
    if (ck + 1 < CPT) stageA((ck + 1) & 1, ck + 1);
    computeC(&ldsA[ck & 1][0], ck);
    asm volatile("s_waitcnt vmcnt(0)" ::: "memory");
    __builtin_amdgcn_s_barrier();
    asm volatile("" ::: "memory");
  }

  #pragma unroll
  for (int mf = 0; mf < Mf; ++mf)
    #pragma unroll
    for (int nf = 0; nf < Nf; ++nf)
      #pragma unroll
      for (int j = 0; j < 4; ++j) {
        int m = wm * WM + mf * 16 + gq * 4 + j;
        int s = q0 + m;
        int gpos;
        if constexpr (KIND == KV) gpos = ((s & 31) << 6) + (s >> 5);
        else gpos = s;
        int p = bbase + gpos;
        int ng = n0 + wn * WN + nf * 16 + l15;
        epilogue_store<EPI>(g, acc[mf][nf][j], p, ng, 0);
      }
}

// ---------------- final avgpool 2x2 -> (2,256,16,32)
__launch_bounds__(256)
__global__ void pool_kernel(const float* __restrict__ op, float* out) {
  int idx = blockIdx.x * 256 + (int)threadIdx.x;   // 0..262143
  int xx = idx & 31, yy = (idx >> 5) & 15, oc = (idx >> 9) & 255, b = idx >> 17;
  size_t p00 = (size_t)b * 2048 + (size_t)(yy * 2) * 64 + xx * 2;
  float v = 0.25f * (op[p00 * 256 + oc] + op[(p00 + 1) * 256 + oc] +
                     op[(p00 + 64) * 256 + oc] + op[(p00 + 65) * 256 + oc]);
  out[idx] = v;
}

// ---------------- host ----------------
extern "C" void kernel_launch(void* const* d_in, const int* in_sizes, int n_in,
                              void* d_out, int out_size, void* d_ws, size_t ws_size,
                              hipStream_t stream) {
  (void)in_sizes; (void)n_in; (void)out_size; (void)ws_size;
  const float* x   = (const float*)d_in[0];
  const float* wz1 = (const float*)d_in[3];  const float* bz1 = (const float*)d_in[4];
  const float* wr1 = (const float*)d_in[5];  const float* br1 = (const float*)d_in[6];
  const float* wq1 = (const float*)d_in[7];  const float* bq1 = (const float*)d_in[8];
  const float* wz2 = (const float*)d_in[9];  const float* bz2 = (const float*)d_in[10];
  const float* wr2 = (const float*)d_in[11]; const float* br2 = (const float*)d_in[12];
  const float* wq2 = (const float*)d_in[13]; const float* bq2 = (const float*)d_in[14];
  const float* wc  = (const float*)d_in[15]; const float* bc  = (const float*)d_in[16];

  char* ws = (char*)d_ws;
  unsigned short* corr0 = (unsigned short*)(ws + CORR0_OFF);
  unsigned short* f1  = (unsigned short*)(ws + F1_OFF);
  unsigned short* f2p = (unsigned short*)(ws + F2_OFF);
  unsigned short* inp = (unsigned short*)(ws + INP_OFF);
  float* h_f32 = (float*)(ws + HF_OFF);
  unsigned short* h_b16 = (unsigned short*)(ws + HB_OFF);
  unsigned short* rh    = (unsigned short*)(ws + RH_OFF);
  unsigned short* zb16  = (unsigned short*)(ws + Z_OFF);
  unsigned short* Cp1 = (unsigned short*)(ws + CP1_OFF);
  unsigned short* Cp2 = (unsigned short*)(ws + CP2_OFF);
  unsigned short* wA1 = (unsigned short*)(ws + WA1_OFF);
  unsigned short* wA2 = (unsigned short*)(ws + WA2_OFF);
  unsigned short* wB1 = (unsigned short*)(ws + WB1_OFF);
  unsigned short* wB2 = (unsigned short*)(ws + WB2_OFF);
  unsigned short* wi1 = (unsigned short*)(ws + WI1_OFF);
  unsigned short* wi2 = (unsigned short*)(ws + WI2_OFF);
  unsigned short* wfn = (unsigned short*)(ws + WFIN_OFF);
  float* outpre = (float*)(ws + OP_OFF);
  float* zp     = (float*)(ws + ZP_OFF);

  prep_kernel<<<8192, 256, 0, stream>>>(x, f1, f2p, h_f32, h_b16, inp, zp);

  {
    WPAll wa;
    wa.wz1 = wz1; wa.wr1 = wr1; wa.wq1 = wq1;
    wa.wz2 = wz2; wa.wr2 = wr2; wa.wq2 = wq2; wa.wc = wc;
    wa.wA1 = wA1; wa.wB1 = wB1; wa.wi1 = wi1;
    wa.wA2 = wA2; wa.wB2 = wB2; wa.wi2 = wi2; wa.wfn = wfn;
    wprep_all<<<43008, 256, 0, stream>>>(wa);
  }

  {  // correlation: per batch (2048x2048) = f1 . f2^T / 16 -> bf16 corr0
    GArgs a = {};
    a.A = (const char*)f1;  a.AstrB = 512; a.AbatchB = 2048L * 512;
    a.B = (const char*)f2p; a.KelB = 512;  a.BbatchB = 2048L * 512;
    a.u0 = corr0; a.CbatchE = 2048L * 2048; a.zp = (const char*)zp;
    kgemm<128,64,2,EC,4,3><<<dim3(16,32,2), 256, 0, stream>>>(a);
  }
  pyrlook_kernel<<<4096, 256, 0, stream>>>(corr0, h_f32, h_b16);

  {  // inp-contribution precompute, half 1 (1x5) -> bf16 Cp1
    GArgs a = {};
    a.A = (const char*)inp; a.AstrB = 256; a.B = (const char*)wi1;
    a.e0 = bz1; a.e1 = br1; a.e2 = bq1; a.u0 = Cp1; a.zp = (const char*)zp;
    tgemm<64,32,4,KH,EP,5,2,4><<<dim3(64,48), 256, 0, stream>>>(a);
  }
  {  // half 2 (5x1) -> bf16 Cp2
    GArgs a = {};
    a.A = (const char*)inp; a.AstrB = 256; a.B = (const char*)wi2;
    a.e0 = bz2; a.e1 = br2; a.e2 = bq2; a.u0 = Cp2; a.zp = (const char*)zp;
    tgemm<64,32,4,KV,EP,5,2,4><<<dim3(64,48), 256, 0, stream>>>(a);
  }

  for (int it = 0; it < 12; ++it) {
    {  // half1 stage A: z & r convs (N=1024), 128x32 tile, 4x1 waves (Mf=2/Nf=2)
      GArgs a = {};
      a.A = (const char*)h_b16; a.AstrB = 1024; a.B = (const char*)wA1;
      a.b0 = Cp1; a.b1 = h_b16; a.u0 = rh; a.u1 = zb16; a.zp = (const char*)zp;
      tgemm<128,32,4,KH,EA,5,8,4><<<dim3(32,32), 256, 0, stream>>>(a);
    }
    {  // half1 stage B: q conv (N=512), 64x32 tile, 4x1 waves (Mf=1/Nf=2)
      GArgs a = {};
      a.A = (const char*)rh; a.AstrB = 1024; a.B = (const char*)wB1;
      a.b0 = Cp1; a.b1 = zb16; a.e2 = h_f32; a.f0 = h_f32; a.u0 = h_b16; a.zp = (const char*)zp;
      tgemm<64,32,4,KH,EB,5,8,4><<<dim3(64,16), 256, 0, stream>>>(a);
    }
    {  // half2 stage A (5x1)
      GArgs a = {};
      a.A = (const char*)h_b16; a.AstrB = 1024; a.B = (const char*)wA2;
      a.b0 = Cp2; a.b1 = h_b16; a.u0 = rh; a.u1 = zb16; a.zp = (const char*)zp;
      tgemm<128,32,4,KV,EA,5,8,4><<<dim3(32,32), 256, 0, stream>>>(a);
    }
    {  // half2 stage B
      GArgs a = {};
      a.A = (const char*)rh; a.AstrB = 1024; a.B = (const char*)wB2;
      a.b0 = Cp2; a.b1 = zb16; a.e2 = h_f32; a.f0 = h_f32; a.u0 = h_b16; a.zp = (const char*)zp;
      tgemm<64,32,4,KV,EB,5,8,4><<<dim3(64,16), 256, 0, stream>>>(a);
    }
  }

  {  // final 3x3 conv 452->256 + relu (2-D halo, 9 taps merged)
    GArgs a = {};
    a.A = (const char*)h_b16; a.AstrB = 1024; a.B = (const char*)wfn;
    a.e0 = bc; a.f0 = outpre; a.zp = (const char*)zp;
    tgemm<64,16,4,KF,EF,9,8,3><<<dim3(64,16), 256, 0, stream>>>(a);
  }
  pool_kernel<<<1024, 256, 0, stream>>>(outpre, (float*)d_out);
}

// Round 11
// 1417.553 us; speedup vs baseline: 1.3477x; 1.3477x over previous
//
#include <hip/hip_runtime.h>
#include <hip/hip_bf16.h>
#include <cstdint>

#define DEV static __device__ __forceinline__

typedef short bf16x8 __attribute__((ext_vector_type(8)));
typedef float f32x4 __attribute__((ext_vector_type(4)));
typedef unsigned short bfu8 __attribute__((ext_vector_type(8)));

// ---------------- workspace layout (bytes) ----------------
constexpr size_t CORR0_OFF = 0;                        // (2,2048,2048) bf16
constexpr size_t LVL1_OFF  = CORR0_OFF + 33554432ull;  // (unused)
constexpr size_t LVL2_OFF  = LVL1_OFF  + 8388608ull;   // (unused)
constexpr size_t LVL3_OFF  = LVL2_OFF  + 2097152ull;   // (unused)
constexpr size_t F1_OFF    = LVL3_OFF  + 524288ull;    // (2,2048,256) bf16
constexpr size_t F2_OFF    = F1_OFF    + 2097152ull;
constexpr size_t INP_OFF   = F2_OFF    + 2097152ull;   // (4096,128) bf16
constexpr size_t HF_OFF    = INP_OFF   + 1048576ull;   // (4096,512) f32
constexpr size_t HB_OFF    = HF_OFF    + 8388608ull;   // (4096,512) bf16
constexpr size_t RH_OFF    = HB_OFF    + 4194304ull;   // (4096,512) bf16
constexpr size_t Z_OFF     = RH_OFF    + 4194304ull;   // (4096,512) bf16 z-gate
constexpr size_t CP1_OFF   = Z_OFF     + 8388608ull;   // (4096,1536) bf16
constexpr size_t CP2_OFF   = CP1_OFF   + 25165824ull;
constexpr size_t WA1_OFF   = CP2_OFF   + 25165824ull;  // (1024,5,512) bf16
constexpr size_t WA2_OFF   = WA1_OFF   + 5242880ull;
constexpr size_t WB1_OFF   = WA2_OFF   + 5242880ull;   // (512,5,512) bf16
constexpr size_t WB2_OFF   = WB1_OFF   + 2621440ull;
constexpr size_t WI1_OFF   = WB2_OFF   + 2621440ull;   // (1536,5,128) bf16
constexpr size_t WI2_OFF   = WI1_OFF   + 1966080ull;
constexpr size_t WFIN_OFF  = WI2_OFF   + 1966080ull;   // (256,9,512) bf16
constexpr size_t OP_OFF    = WFIN_OFF  + 2359296ull;   // (4096,256) f32
constexpr size_t ZP_OFF    = OP_OFF    + 4194304ull;   // 1024 B zero page

DEV unsigned short f2bf(float f) {
  unsigned int u = __float_as_uint(f);
  u += 0x7fffu + ((u >> 16) & 1u);
  return (unsigned short)(u >> 16);
}
DEV float bf2f(unsigned short u) { return __uint_as_float(((unsigned)u) << 16); }

DEV void gload16(const void* src, void* dst) {
  __builtin_amdgcn_global_load_lds(
      (const __attribute__((address_space(1))) void*)src,
      (__attribute__((address_space(3))) void*)dst, 16, 0, 0);
}

// ---------------- prep: f1/f2 bf16, tanh->h[324..451], relu->inp, pads, zero page
__launch_bounds__(256)
__global__ void prep_kernel(const float* __restrict__ x, unsigned short* f1, unsigned short* f2,
                            float* h_f32, unsigned short* h_b16, unsigned short* inp, float* zp) {
  int bx = blockIdx.x;                 // 0..8191
  int s = bx >> 11, n = bx & 2047, c = (int)threadIdx.x;
  float v = x[((size_t)(s * 2048 + n)) * 256 + c];
  int b = s >> 1;
  unsigned short bv = f2bf(v);
  size_t p = (size_t)b * 2048 + n;
  if (s & 1) {
    f2[p * 256 + c] = bv;
  } else {
    f1[p * 256 + c] = bv;
    if (c < 128) {
      float tv = tanhf(v);
      h_f32[p * 512 + 324 + c] = tv;
      h_b16[p * 512 + 324 + c] = f2bf(tv);
    } else {
      float rv = fmaxf(v, 0.f);
      inp[p * 128 + (c - 128)] = f2bf(rv);
    }
    if (c < 60) { h_f32[p * 512 + 452 + c] = 0.f; h_b16[p * 512 + 452 + c] = 0; }
  }
  if (bx == 0) zp[c] = 0.f;
}

// ---------------- merged weight repack (7 segments in one launch)
DEV void wprep_body(const float* s0, const float* s1, const float* s2,
                    unsigned short* dst, long rel, int TK, int K, int Kvalid, int icOff,
                    int sOC, int sIC) {
  long idx = rel * 256 + threadIdx.x;
  int n = (int)(idx / TK);
  int rem = (int)(idx % TK);
  int t = rem / K, k = rem % K;
  int sec = n >> 9, ocl = n & 511;
  const float* sp = (sec == 0) ? s0 : (sec == 1 ? s1 : s2);
  float v = 0.f;
  if (ocl < 452 && k < Kvalid) v = sp[(size_t)ocl * sOC + (size_t)(icOff + k) * sIC + t];
  dst[idx] = f2bf(v);
}

struct WPAll {
  const float *wz1, *wr1, *wq1, *wz2, *wr2, *wq2, *wc;
  unsigned short *wA1, *wB1, *wi1, *wA2, *wB2, *wi2, *wfn;
};

__launch_bounds__(256)
__global__ void wprep_all(WPAll a) {
  long b = blockIdx.x;
  if      (b < 10240) wprep_body(a.wz1, a.wr1, nullptr, a.wA1, b,         5*512, 512, 452, 0,   2900, 5);
  else if (b < 15360) wprep_body(a.wq1, nullptr, nullptr, a.wB1, b-10240, 5*512, 512, 452, 0,   2900, 5);
  else if (b < 19200) wprep_body(a.wz1, a.wr1, a.wq1,   a.wi1, b-15360,   5*128, 128, 128, 452, 2900, 5);
  else if (b < 29440) wprep_body(a.wz2, a.wr2, nullptr, a.wA2, b-19200,   5*512, 512, 452, 0,   2900, 5);
  else if (b < 34560) wprep_body(a.wq2, nullptr, nullptr, a.wB2, b-29440, 5*512, 512, 452, 0,   2900, 5);
  else if (b < 38400) wprep_body(a.wz2, a.wr2, a.wq2,   a.wi2, b-34560,   5*128, 128, 128, 452, 2900, 5);
  else                wprep_body(a.wc,  nullptr, nullptr, a.wfn, b-38400, 9*512, 512, 452, 0,   4068, 9);
}

// ---------------- fused pyramid + corr lookup (pyramid stays in LDS)
__launch_bounds__(256)
__global__ void pyrlook_kernel(const unsigned short* __restrict__ corr0,
                               float* h_f32, unsigned short* h_b16) {
  __shared__ float s0[2048];
  __shared__ float s1[512];
  __shared__ float s2[128];
  __shared__ float s3[32];
  int bn = blockIdx.x, tid = (int)threadIdx.x;
  bfu8 v8 = ((const bfu8*)(corr0 + (size_t)bn * 2048))[tid];
  #pragma unroll
  for (int j = 0; j < 8; ++j) s0[tid * 8 + j] = bf2f(v8[j]);
  __syncthreads();
  for (int o = tid; o < 512; o += 256) {
    int yy = o >> 5, xx = o & 31;
    s1[o] = 0.25f * (s0[(yy*2)*64 + xx*2] + s0[(yy*2)*64 + xx*2 + 1] +
                     s0[(yy*2+1)*64 + xx*2] + s0[(yy*2+1)*64 + xx*2 + 1]);
  }
  __syncthreads();
  if (tid < 128) {
    int yy = tid >> 4, xx = tid & 15;
    s2[tid] = 0.25f * (s1[(yy*2)*32 + xx*2] + s1[(yy*2)*32 + xx*2 + 1] +
                       s1[(yy*2+1)*32 + xx*2] + s1[(yy*2+1)*32 + xx*2 + 1]);
  }
  __syncthreads();
  if (tid < 32) {
    int yy = tid >> 3, xx = tid & 7;
    s3[tid] = 0.25f * (s2[(yy*2)*16 + xx*2] + s2[(yy*2)*16 + xx*2 + 1] +
                       s2[(yy*2+1)*16 + xx*2] + s2[(yy*2+1)*16 + xx*2 + 1]);
  }
  __syncthreads();
  int x = bn & 63, y = (bn >> 6) & 31;
  for (int ch = tid; ch < 324; ch += 256) {
    int lvl = ch / 81, w = ch % 81;
    int di = w / 9 - 4, dj = w % 9 - 4;
    const float* sl = (lvl == 0) ? s0 : (lvl == 1) ? s1 : (lvl == 2) ? s2 : s3;
    int wl = 64 >> lvl, hl = 32 >> lvl;
    float sx = (float)x / (float)(1 << lvl) + (float)di;
    float sy = (float)y / (float)(1 << lvl) + (float)dj;
    float fx0 = floorf(sx), fy0 = floorf(sy);
    int x0 = (int)fx0, y0 = (int)fy0;
    float wx1 = sx - fx0, wx0 = 1.f - wx1;
    float wy1 = sy - fy0, wy0 = 1.f - wy1;
    float acc = 0.f;
    if (x0 >= 0 && x0 < wl && y0 >= 0 && y0 < hl)         acc += sl[y0*wl + x0] * wx0 * wy0;
    if (x0+1 >= 0 && x0+1 < wl && y0 >= 0 && y0 < hl)     acc += sl[y0*wl + x0+1] * wx1 * wy0;
    if (x0 >= 0 && x0 < wl && y0+1 >= 0 && y0+1 < hl)     acc += sl[(y0+1)*wl + x0] * wx0 * wy1;
    if (x0+1 >= 0 && x0+1 < wl && y0+1 >= 0 && y0+1 < hl) acc += sl[(y0+1)*wl + x0+1] * wx1 * wy1;
    h_f32[(size_t)bn * 512 + ch] = acc;
    h_b16[(size_t)bn * 512 + ch] = f2bf(acc);
  }
}

// ---------------- GEMM-conv engines ----------------
constexpr int KN = 0, KH = 1, KV = 2, KF = 3;     // shift kinds
constexpr int EC = 0, EP = 1, EA = 2, EB = 3, EF = 4;  // epilogues

struct GArgs {
  const char* A; int AstrB; long AbatchB;
  const char* B; int KelB;  long BbatchB;
  const float* e0; const float* e1; const float* e2;
  const unsigned short* b0;          // bf16 Cp source for EA/EB
  const unsigned short* b1;          // bf16 aux read (h_b16 for EA, z for EB)
  float* f0; unsigned short* u0; unsigned short* u1;
  long CbatchE;
  const char* zp;
};

template<int MT>
DEV void stage_act(const char* Ab, int AstrB, char* ldsbuf, int ckOff, int p0) {
  #pragma unroll
  for (int it = 0; it < (MT * 8) / 256; ++it) {
    int gi = it * 256 + (int)threadIdx.x;
    int row = gi >> 3, gs = gi & 7;
    int gl = gs ^ (row & 7);
    int p = p0 + row;
    const char* src = Ab + (size_t)p * (size_t)AstrB + ckOff + gl * 16;
    char* dst = ldsbuf + ((size_t)(it * 256 + ((int)threadIdx.x & ~63)) * 16);
    gload16(src, dst);
  }
}

template<int NT>
DEV void stage_wk(const char* Bb, int KelB, char* ldsbuf, int ckOff, int n0) {
  #pragma unroll
  for (int it = 0; it < (NT * 8) / 256; ++it) {
    int gi = it * 256 + (int)threadIdx.x;
    int row = gi >> 3, gs = gi & 7;
    int gl = gs ^ (row & 7);
    int n = n0 + row;
    const char* src = Bb + (size_t)n * (size_t)KelB + ckOff + gl * 16;
    char* dst = ldsbuf + ((size_t)(it * 256 + ((int)threadIdx.x & ~63)) * 16);
    gload16(src, dst);
  }
}

template<int Mf, int Nf, int WM, int WN>
DEV void compute_chunk(const char* lA, const char* lB, f32x4 acc[Mf][Nf], int wm, int wn) {
  const int lane = (int)threadIdx.x & 63;
  const int l15 = lane & 15, g = lane >> 4;
  #pragma unroll
  for (int ks = 0; ks < 2; ++ks) {
    bf16x8 a[Mf], b[Nf];
    int q = ks * 4 + g;
    #pragma unroll
    for (int mf = 0; mf < Mf; ++mf) {
      int r = wm * WM + mf * 16 + l15;
      a[mf] = *(const bf16x8*)(lA + r * 128 + ((q ^ (r & 7)) * 16));
    }
    #pragma unroll
    for (int nf = 0; nf < Nf; ++nf) {
      int r = wn * WN + nf * 16 + l15;
      b[nf] = *(const bf16x8*)(lB + r * 128 + ((q ^ (r & 7)) * 16));
    }
    #pragma unroll
    for (int mf = 0; mf < Mf; ++mf)
      #pragma unroll
      for (int nf = 0; nf < Nf; ++nf)
        acc[mf][nf] = __builtin_amdgcn_mfma_f32_16x16x32_bf16(a[mf], b[nf], acc[mf][nf], 0, 0, 0);
  }
}

// shared epilogue
template<int EPI>
DEV void epilogue_store(const GArgs& g, float v, int p, int ng, int bz) {
  if constexpr (EPI == EC) {
    g.u0[(size_t)bz * (size_t)g.CbatchE + (size_t)p * 2048 + ng] = f2bf(v * 0.0625f);
  } else if constexpr (EPI == EP) {
    float bias;
    if (ng < 512)       bias = (ng < 452) ? g.e0[ng] : 0.f;
    else if (ng < 1024) bias = (ng - 512 < 452) ? g.e1[ng - 512] : 0.f;
    else                bias = (ng - 1024 < 452) ? g.e2[ng - 1024] : 0.f;
    g.u0[(size_t)p * 1536 + ng] = f2bf(v + bias);
  } else if constexpr (EPI == EA) {
    float pre = v + bf2f(g.b0[(size_t)p * 1536 + ng]);
    float s = 1.f / (1.f + __expf(-pre));
    if (ng < 512) {
      g.u1[(size_t)p * 512 + ng] = f2bf(s);                       // z gate (bf16)
    } else {
      int oc = ng - 512;
      float rh = s * bf2f(g.b1[(size_t)p * 512 + oc]);            // sigmoid(r) * h_b16
      g.u0[(size_t)p * 512 + oc] = f2bf(rh);
    }
  } else if constexpr (EPI == EB) {
    float pre = v + bf2f(g.b0[(size_t)p * 1536 + 1024 + ng]);
    float e = __expf(-2.f * fabsf(pre));
    float tt = (1.f - e) / (1.f + e);
    float qv = (pre < 0.f) ? -tt : tt;
    float z = bf2f(g.b1[(size_t)p * 512 + ng]);                   // z gate (bf16)
    float ho = g.e2[(size_t)p * 512 + ng];                        // f32 master h
    float hn = (1.f - z) * ho + z * qv;
    g.f0[(size_t)p * 512 + ng] = hn;
    g.u0[(size_t)p * 512 + ng] = f2bf(hn);
  } else {  // EF
    float r = fmaxf(v + g.e0[ng], 0.f);
    g.f0[(size_t)p * 256 + ng] = r;
  }
}

// plain per-chunk GEMM (corr only: KN, no tap shifts), bf16 output
template<int MT, int NT, int WSM, int EPI, int CPT, int MINB>
__launch_bounds__(256, MINB)
__global__ void kgemm(GArgs g) {
  constexpr int WSN = 4 / WSM;
  constexpr int WM = MT / WSM, WN = NT / WSN, Mf = WM / 16, Nf = WN / 16;
  constexpr int BUFB = (MT + NT) * 128;
  __shared__ __attribute__((aligned(16))) char lds[2 * BUFB];
  const int p0 = blockIdx.x * MT, n0 = blockIdx.y * NT;
  const int bz = blockIdx.z;
  const char* Ab = g.A + (size_t)bz * (size_t)g.AbatchB;
  const char* Bb = g.B + (size_t)bz * (size_t)g.BbatchB;
  const int wave = (int)threadIdx.x >> 6;
  const int wm = wave / WSN, wn = wave % WSN;
  f32x4 acc[Mf][Nf] = {};

  auto do_stage = [&](int buf, int c) {
    char* base = lds + (size_t)buf * BUFB;
    stage_act<MT>(Ab, g.AstrB, base, c * 128, p0);
    stage_wk<NT>(Bb, g.KelB, base + MT * 128, c * 128, n0);
  };

  do_stage(0, 0);
  asm volatile("s_waitcnt vmcnt(0)" ::: "memory");
  __builtin_amdgcn_s_barrier();
  asm volatile("" ::: "memory");

  #pragma unroll 1
  for (int c = 0; c < CPT; ++c) {
    int cur = c & 1;
    if (c + 1 < CPT) do_stage(cur ^ 1, c + 1);
    const char* base = lds + (size_t)cur * BUFB;
    compute_chunk<Mf, Nf, WM, WN>(base, base + MT * 128, acc, wm, wn);
    asm volatile("s_waitcnt vmcnt(0)" ::: "memory");
    __builtin_amdgcn_s_barrier();
    asm volatile("" ::: "memory");
  }

  const int lane = (int)threadIdx.x & 63;
  const int l15 = lane & 15, gq = lane >> 4;
  #pragma unroll
  for (int mf = 0; mf < Mf; ++mf)
    #pragma unroll
    for (int nf = 0; nf < Nf; ++nf)
      #pragma unroll
      for (int j = 0; j < 4; ++j) {
        int p = p0 + wm * WM + mf * 16 + gq * 4 + j;
        int ng = n0 + wn * WN + nf * 16 + l15;
        epilogue_store<EPI>(g, acc[mf][nf][j], p, ng, bz);
      }
}

// tap-merged single-buffer conv GEMM. WSM picks the wave grid (WSM x 4/WSM);
// occupancy (4 blocks/CU, 16 waves/CU) outranks fragment reuse (R7/R8 lesson);
// within that, maximize Mf*Nf/(Mf+Nf). B staged via LDS (R10: direct-global B
// regressed — per-fragment L2 latency on the MFMA critical path).
template<int MT, int NT, int WSM, int KIND, int EPI, int TAPS, int CPT, int MINB>
__launch_bounds__(256, MINB)
__global__ void tgemm(GArgs g) {
  constexpr int Gsz = (KIND == KV) ? 32 : 64;
  constexpr int G   = (KIND == KF) ? 3 : MT / Gsz;
  constexpr int S   = (KIND == KF) ? 66 : Gsz + 4;
  constexpr int RA  = G * S;
  constexpr int RAP = (RA + 7) & ~7;                 // pad to whole waves
  constexpr int RB  = TAPS * NT;
  constexpr int ITA = (RAP * 8 + 255) / 256;
  constexpr int ITB = (RB * 8 + 255) / 256;
  constexpr int WSN = 4 / WSM;
  constexpr int WM = MT / WSM, WN = NT / WSN;
  constexpr int Mf = WM / 16, Nf = WN / 16;
  __shared__ __attribute__((aligned(16))) char ldsA[RAP * 128];
  __shared__ __attribute__((aligned(16))) char ldsB[RB * 128];

  const int tid = (int)threadIdx.x;
  const int pg = blockIdx.x * MT;
  const int bz = pg >> 11;
  const int q0 = pg & 2047;
  const int bbase = bz << 11;
  const int n0 = blockIdx.y * NT;
  const char* Ab = g.A + (size_t)bbase * (size_t)g.AstrB;
  const int wave = tid >> 6;
  const int wm = wave / WSN, wn = wave % WSN;
  const int lane = tid & 63;
  const int l15 = lane & 15, gq = lane >> 4;
  f32x4 acc[Mf][Nf] = {};

  auto stageA = [&](int ck) {
    #pragma unroll
    for (int it = 0; it < ITA; ++it) {
      int gi = it * 256 + tid;
      if (ITA * 256 > RAP * 8 && gi >= RAP * 8) continue;   // whole-wave guard
      int sr = gi >> 3, gs = gi & 7;
      int gl = gs ^ (sr & 7);
      bool valid; int gpos;
      if constexpr (KIND == KF) {
        int grp = sr / 66, qq = sr - grp * 66;
        int y = (q0 >> 6) + grp - 1, x = qq - 1;
        valid = (sr < RA) && (qq >= 1) && (qq < 65) && ((unsigned)y < 32u);
        gpos = (y << 6) + x;
      } else {
        int grp = (G == 1) ? 0 : (sr / S);
        int qq = sr - grp * S;
        valid = (sr < RA) && (qq >= 2) && (qq < Gsz + 2);
        int s = q0 + grp * Gsz + (qq - 2);
        if constexpr (KIND == KH) gpos = s;
        else gpos = ((s & 31) << 6) + (s >> 5);
      }
      const char* src = valid ? (Ab + (size_t)gpos * (size_t)g.AstrB + ck * 128 + gl * 16)
                              : (g.zp + gl * 16);
      gload16(src, &ldsA[(size_t)(it * 256 + (tid & ~63)) * 16]);
    }
  };
  auto stageBf = [&](int ck) {
    #pragma unroll
    for (int it = 0; it < ITB; ++it) {
      int gi = it * 256 + tid;
      if (ITB * 256 > RB * 8 && gi >= RB * 8) continue;
      int rb = gi >> 3, gs = gi & 7;
      int gl = gs ^ (rb & 7);
      int t = rb / NT, nl = rb - t * NT;
      const char* src = g.B + ((size_t)(n0 + nl) * TAPS + t) * (size_t)g.KelB + ck * 128 + gl * 16;
      gload16(src, &ldsB[(size_t)(it * 256 + (tid & ~63)) * 16]);
    }
  };

  auto computeC = [&]() {
    #pragma unroll
    for (int t = 0; t < TAPS; ++t) {
      #pragma unroll
      for (int ks = 0; ks < 2; ++ks) {
        int q = ks * 4 + gq;
        bf16x8 a[Mf], b[Nf];
        #pragma unroll
        for (int mf = 0; mf < Mf; ++mf) {
          int m = wm * WM + mf * 16 + l15;
          int r;
          if constexpr (KIND == KF) r = (t / 3) * 66 + (m & 63) + (t % 3);
          else r = (m / Gsz) * S + (m % Gsz) + t;
          a[mf] = *(const bf16x8*)(&ldsA[r * 128 + ((q ^ (r & 7)) * 16)]);
        }
        #pragma unroll
        for (int nf = 0; nf < Nf; ++nf) {
          int rb = t * NT + wn * WN + nf * 16 + l15;
          b[nf] = *(const bf16x8*)(&ldsB[rb * 128 + ((q ^ (rb & 7)) * 16)]);
        }
        #pragma unroll
        for (int mf = 0; mf < Mf; ++mf)
          #pragma unroll
          for (int nf = 0; nf < Nf; ++nf)
            acc[mf][nf] = __builtin_amdgcn_mfma_f32_16x16x32_bf16(a[mf], b[nf], acc[mf][nf], 0, 0, 0);
      }
    }
  };

  stageA(0); stageBf(0);
  asm volatile("s_waitcnt vmcnt(0)" ::: "memory");
  __builtin_amdgcn_s_barrier();
  asm volatile("" ::: "memory");

  #pragma unroll 1
  for (int ck = 0; ck < CPT; ++ck) {
    computeC();
    if (ck + 1 < CPT) {
      asm volatile("" ::: "memory");
      __builtin_amdgcn_s_barrier();        // all waves done reading this chunk
      asm volatile("" ::: "memory");
      stageA(ck + 1); stageBf(ck + 1);
      asm volatile("s_waitcnt vmcnt(0)" ::: "memory");
      __builtin_amdgcn_s_barrier();        // next chunk staged
      asm volatile("" ::: "memory");
    }
  }

  #pragma unroll
  for (int mf = 0; mf < Mf; ++mf)
    #pragma unroll
    for (int nf = 0; nf < Nf; ++nf)
      #pragma unroll
      for (int j = 0; j < 4; ++j) {
        int m = wm * WM + mf * 16 + gq * 4 + j;
        int s = q0 + m;
        int gpos;
        if constexpr (KIND == KV) gpos = ((s & 31) << 6) + (s >> 5);
        else gpos = s;
        int p = bbase + gpos;
        int ng = n0 + wn * WN + nf * 16 + l15;
        epilogue_store<EPI>(g, acc[mf][nf][j], p, ng, 0);
      }
}

// ---------------- final avgpool 2x2 -> (2,256,16,32)
__launch_bounds__(256)
__global__ void pool_kernel(const float* __restrict__ op, float* out) {
  int idx = blockIdx.x * 256 + (int)threadIdx.x;   // 0..262143
  int xx = idx & 31, yy = (idx >> 5) & 15, oc = (idx >> 9) & 255, b = idx >> 17;
  size_t p00 = (size_t)b * 2048 + (size_t)(yy * 2) * 64 + xx * 2;
  float v = 0.25f * (op[p00 * 256 + oc] + op[(p00 + 1) * 256 + oc] +
                     op[(p00 + 64) * 256 + oc] + op[(p00 + 65) * 256 + oc]);
  out[idx] = v;
}

// ---------------- host ----------------
extern "C" void kernel_launch(void* const* d_in, const int* in_sizes, int n_in,
                              void* d_out, int out_size, void* d_ws, size_t ws_size,
                              hipStream_t stream) {
  (void)in_sizes; (void)n_in; (void)out_size; (void)ws_size;
  const float* x   = (const float*)d_in[0];
  const float* wz1 = (const float*)d_in[3];  const float* bz1 = (const float*)d_in[4];
  const float* wr1 = (const float*)d_in[5];  const float* br1 = (const float*)d_in[6];
  const float* wq1 = (const float*)d_in[7];  const float* bq1 = (const float*)d_in[8];
  const float* wz2 = (const float*)d_in[9];  const float* bz2 = (const float*)d_in[10];
  const float* wr2 = (const float*)d_in[11]; const float* br2 = (const float*)d_in[12];
  const float* wq2 = (const float*)d_in[13]; const float* bq2 = (const float*)d_in[14];
  const float* wc  = (const float*)d_in[15]; const float* bc  = (const float*)d_in[16];

  char* ws = (char*)d_ws;
  unsigned short* corr0 = (unsigned short*)(ws + CORR0_OFF);
  unsigned short* f1  = (unsigned short*)(ws + F1_OFF);
  unsigned short* f2p = (unsigned short*)(ws + F2_OFF);
  unsigned short* inp = (unsigned short*)(ws + INP_OFF);
  float* h_f32 = (float*)(ws + HF_OFF);
  unsigned short* h_b16 = (unsigned short*)(ws + HB_OFF);
  unsigned short* rh    = (unsigned short*)(ws + RH_OFF);
  unsigned short* zb16  = (unsigned short*)(ws + Z_OFF);
  unsigned short* Cp1 = (unsigned short*)(ws + CP1_OFF);
  unsigned short* Cp2 = (unsigned short*)(ws + CP2_OFF);
  unsigned short* wA1 = (unsigned short*)(ws + WA1_OFF);
  unsigned short* wA2 = (unsigned short*)(ws + WA2_OFF);
  unsigned short* wB1 = (unsigned short*)(ws + WB1_OFF);
  unsigned short* wB2 = (unsigned short*)(ws + WB2_OFF);
  unsigned short* wi1 = (unsigned short*)(ws + WI1_OFF);
  unsigned short* wi2 = (unsigned short*)(ws + WI2_OFF);
  unsigned short* wfn = (unsigned short*)(ws + WFIN_OFF);
  float* outpre = (float*)(ws + OP_OFF);
  float* zp     = (float*)(ws + ZP_OFF);

  prep_kernel<<<8192, 256, 0, stream>>>(x, f1, f2p, h_f32, h_b16, inp, zp);

  {
    WPAll wa;
    wa.wz1 = wz1; wa.wr1 = wr1; wa.wq1 = wq1;
    wa.wz2 = wz2; wa.wr2 = wr2; wa.wq2 = wq2; wa.wc = wc;
    wa.wA1 = wA1; wa.wB1 = wB1; wa.wi1 = wi1;
    wa.wA2 = wA2; wa.wB2 = wB2; wa.wi2 = wi2; wa.wfn = wfn;
    wprep_all<<<43008, 256, 0, stream>>>(wa);
  }

  {  // correlation: per batch (2048x2048) = f1 . f2^T / 16 -> bf16 corr0
     // 128x64 tile, 2x2 waves (Mf=4/Nf=2), grid 1024 -> 3 blocks/CU
    GArgs a = {};
    a.A = (const char*)f1;  a.AstrB = 512; a.AbatchB = 2048L * 512;
    a.B = (const char*)f2p; a.KelB = 512;  a.BbatchB = 2048L * 512;
    a.u0 = corr0; a.CbatchE = 2048L * 2048; a.zp = (const char*)zp;
    kgemm<128,64,2,EC,4,3><<<dim3(16,32,2), 256, 0, stream>>>(a);
  }
  pyrlook_kernel<<<4096, 256, 0, stream>>>(corr0, h_f32, h_b16);

  {  // inp-contribution precompute, half 1 (1x5) -> bf16 Cp1
    GArgs a = {};
    a.A = (const char*)inp; a.AstrB = 256; a.B = (const char*)wi1; a.KelB = 256;
    a.e0 = bz1; a.e1 = br1; a.e2 = bq1; a.u0 = Cp1; a.zp = (const char*)zp;
    tgemm<64,32,2,KH,EP,5,2,4><<<dim3(64,48), 256, 0, stream>>>(a);
  }
  {  // half 2 (5x1) -> bf16 Cp2
    GArgs a = {};
    a.A = (const char*)inp; a.AstrB = 256; a.B = (const char*)wi2; a.KelB = 256;
    a.e0 = bz2; a.e1 = br2; a.e2 = bq2; a.u0 = Cp2; a.zp = (const char*)zp;
    tgemm<64,32,2,KV,EP,5,2,4><<<dim3(64,48), 256, 0, stream>>>(a);
  }

  for (int it = 0; it < 12; ++it) {
    {  // half1 stage A: z & r convs (N=1024), 128x32 tile, 4x1 waves -> Mf=2/Nf=2
      GArgs a = {};
      a.A = (const char*)h_b16; a.AstrB = 1024; a.B = (const char*)wA1; a.KelB = 1024;
      a.b0 = Cp1; a.b1 = h_b16; a.u0 = rh; a.u1 = zb16; a.zp = (const char*)zp;
      tgemm<128,32,4,KH,EA,5,8,4><<<dim3(32,32), 256, 0, stream>>>(a);
    }
    {  // half1 stage B: q conv (N=512), 64x32 tile
      GArgs a = {};
      a.A = (const char*)rh; a.AstrB = 1024; a.B = (const char*)wB1; a.KelB = 1024;
      a.b0 = Cp1; a.b1 = zb16; a.e2 = h_f32; a.f0 = h_f32; a.u0 = h_b16; a.zp = (const char*)zp;
      tgemm<64,32,2,KH,EB,5,8,4><<<dim3(64,16), 256, 0, stream>>>(a);
    }
    {  // half2 stage A (5x1)
      GArgs a = {};
      a.A = (const char*)h_b16; a.AstrB = 1024; a.B = (const char*)wA2; a.KelB = 1024;
      a.b0 = Cp2; a.b1 = h_b16; a.u0 = rh; a.u1 = zb16; a.zp = (const char*)zp;
      tgemm<128,32,4,KV,EA,5,8,4><<<dim3(32,32), 256, 0, stream>>>(a);
    }
    {  // half2 stage B
      GArgs a = {};
      a.A = (const char*)rh; a.AstrB = 1024; a.B = (const char*)wB2; a.KelB = 1024;
      a.b0 = Cp2; a.b1 = zb16; a.e2 = h_f32; a.f0 = h_f32; a.u0 = h_b16; a.zp = (const char*)zp;
      tgemm<64,32,2,KV,EB,5,8,4><<<dim3(64,16), 256, 0, stream>>>(a);
    }
  }

  {  // final 3x3 conv 452->256 + relu (2-D halo, 9 taps merged)
    GArgs a = {};
    a.A = (const char*)h_b16; a.AstrB = 1024; a.B = (const char*)wfn; a.KelB = 1024;
    a.e0 = bc; a.f0 = outpre; a.zp = (const char*)zp;
    tgemm<64,16,4,KF,EF,9,8,3><<<dim3(64,16), 256, 0, stream>>>(a);
  }
  pool_kernel<<<1024, 256, 0, stream>>>(outpre, (float*)d_out);
}